// Round 1
// baseline (858.371 us; speedup 1.0000x reference)
//
#include <hip/hip_runtime.h>

// HeteroConv copy_u + segment_sum:
//   out[dst[e], :] += src_emb[src[e], :]  for e in [0, E)
// src_emb: [N_SRC, 64] f32; edge_src/edge_dst: [E] int; out: [N_DST, 64] f32.
//
// Layout: 16 threads per edge, each handling one float4 (4 feats).
// Gather is coalesced (16 lanes read 16 consecutive float4 of one row,
// 4 edges per wave). Scatter via 4x atomicAdd per thread.

__global__ void hetero_conv_scatter(const float* __restrict__ src_emb,
                                    const int* __restrict__ edge_src,
                                    const int* __restrict__ edge_dst,
                                    float* __restrict__ out,
                                    int n_edges) {
    int tid = blockIdx.x * blockDim.x + threadIdx.x;
    int e = tid >> 4;          // edge index
    int q = tid & 15;          // which float4 within the 64-float row
    if (e >= n_edges) return;

    int s = edge_src[e];
    int d = edge_dst[e];

    const float4* srow = reinterpret_cast<const float4*>(src_emb);
    float4 v = srow[(size_t)s * 16 + q];

    float* orow = out + (size_t)d * 64 + (size_t)q * 4;
    atomicAdd(orow + 0, v.x);
    atomicAdd(orow + 1, v.y);
    atomicAdd(orow + 2, v.z);
    atomicAdd(orow + 3, v.w);
}

extern "C" void kernel_launch(void* const* d_in, const int* in_sizes, int n_in,
                              void* d_out, int out_size, void* d_ws, size_t ws_size,
                              hipStream_t stream) {
    const float* src_emb = (const float*)d_in[0];
    const int* edge_src  = (const int*)d_in[1];
    const int* edge_dst  = (const int*)d_in[2];
    // d_in[3] is num_dst (scalar); out_size = num_dst * 64 already.
    float* out = (float*)d_out;

    int n_edges = in_sizes[1];

    // Output must be zeroed every call (harness poisons once, never re-poisons).
    hipMemsetAsync(d_out, 0, (size_t)out_size * sizeof(float), stream);

    int total_threads = n_edges * 16;
    int block = 256;
    int grid = (total_threads + block - 1) / block;
    hetero_conv_scatter<<<grid, block, 0, stream>>>(src_emb, edge_src, edge_dst,
                                                    out, n_edges);
}

// Round 2
// 435.899 us; speedup vs baseline: 1.9692x; 1.9692x over previous
//
#include <hip/hip_runtime.h>

// HeteroConv copy_u + segment_sum, CSR-rebuild formulation:
//   out[d, :] = sum_{e: dst[e]==d} src_emb[src[e], :]
// Instead of 64M float atomics (round-1: 1 GB atomic write traffic,
// atomic-RMW bound at 858us), build a dst-sorted edge list each call:
//   1) histogram(edge_dst)          -> counts[N]
//   2) exclusive scan               -> offsets[N+1], cursor[N]
//   3) scatter edge_src by dst      -> sorted_src[E]
//   4) per-node accumulate (1 wave/node, lane=feature, register acc,
//      single plain store per output element)

// ---- phase 1: histogram ----
__global__ void hist_kernel(const int* __restrict__ edst,
                            int* __restrict__ counts, int n) {
    int i = blockIdx.x * blockDim.x + threadIdx.x;
    if (i < n) atomicAdd(&counts[edst[i]], 1);
}

// ---- phase 2: single-block exclusive scan over counts -> offsets, cursor ----
__global__ void scan_kernel(const int* __restrict__ counts,
                            int* __restrict__ offsets,
                            int* __restrict__ cursor, int n) {
    const int T = 1024;
    int t = threadIdx.x;
    int chunk = (n + T - 1) / T;
    int begin = t * chunk;
    int end = begin + chunk < n ? begin + chunk : n;

    int s = 0;
    for (int i = begin; i < end; ++i) s += counts[i];

    __shared__ int sums[T];
    sums[t] = s;
    __syncthreads();
    // Hillis-Steele inclusive scan (read-before-write separated by barriers)
    for (int off = 1; off < T; off <<= 1) {
        int v = (t >= off) ? sums[t - off] : 0;
        __syncthreads();
        sums[t] += v;
        __syncthreads();
    }
    int run = (t == 0) ? 0 : sums[t - 1];  // exclusive prefix for this chunk

    for (int i = begin; i < end; ++i) {
        offsets[i] = run;
        cursor[i] = run;
        run += counts[i];
    }
    if (t == T - 1) offsets[n] = run;  // == total edge count
}

// ---- phase 3: scatter edge_src into dst-sorted positions ----
__global__ void scatter_kernel(const int* __restrict__ esrc,
                               const int* __restrict__ edst,
                               int* __restrict__ cursor,
                               int* __restrict__ sorted_src, int n) {
    int i = blockIdx.x * blockDim.x + threadIdx.x;
    if (i < n) {
        int pos = atomicAdd(&cursor[edst[i]], 1);
        sorted_src[pos] = esrc[i];
    }
}

// ---- phase 4: per-node accumulation. 1 wave per node, lane = feature ----
__global__ void accum_kernel(const float* __restrict__ src_emb,
                             const int* __restrict__ offsets,
                             const int* __restrict__ sorted_src,
                             float* __restrict__ out, int n_dst) {
    int node = blockIdx.x * (blockDim.x >> 6) + (threadIdx.x >> 6);
    int f = threadIdx.x & 63;
    if (node >= n_dst) return;

    int start = offsets[node];
    int end = offsets[node + 1];

    float acc = 0.f;
    for (int j = start; j < end; ++j) {
        int s = sorted_src[j];                    // wave-uniform broadcast load
        acc += src_emb[(size_t)s * 64 + f];       // 64 lanes -> 256B coalesced
    }
    out[(size_t)node * 64 + f] = acc;             // plain store, no atomics
}

// ---- fallback (ws too small): round-1 atomic version ----
__global__ void atomic_scatter_kernel(const float* __restrict__ src_emb,
                                      const int* __restrict__ esrc,
                                      const int* __restrict__ edst,
                                      float* __restrict__ out, int n_edges) {
    int tid = blockIdx.x * blockDim.x + threadIdx.x;
    int e = tid >> 4;
    int q = tid & 15;
    if (e >= n_edges) return;
    int s = esrc[e];
    int d = edst[e];
    const float4* srow = reinterpret_cast<const float4*>(src_emb);
    float4 v = srow[(size_t)s * 16 + q];
    float* orow = out + (size_t)d * 64 + (size_t)q * 4;
    atomicAdd(orow + 0, v.x);
    atomicAdd(orow + 1, v.y);
    atomicAdd(orow + 2, v.z);
    atomicAdd(orow + 3, v.w);
}

extern "C" void kernel_launch(void* const* d_in, const int* in_sizes, int n_in,
                              void* d_out, int out_size, void* d_ws, size_t ws_size,
                              hipStream_t stream) {
    const float* src_emb = (const float*)d_in[0];
    const int* edge_src  = (const int*)d_in[1];
    const int* edge_dst  = (const int*)d_in[2];
    float* out = (float*)d_out;

    const int n_edges = in_sizes[1];
    const int n_dst   = out_size / 64;   // D = 64

    // workspace layout (ints)
    size_t need = ((size_t)3 * n_dst + 1 + n_edges) * sizeof(int);
    if (ws_size < need) {
        // fallback: atomic formulation
        hipMemsetAsync(d_out, 0, (size_t)out_size * sizeof(float), stream);
        int total = n_edges * 16;
        atomic_scatter_kernel<<<(total + 255) / 256, 256, 0, stream>>>(
            src_emb, edge_src, edge_dst, out, n_edges);
        return;
    }

    int* counts     = (int*)d_ws;                 // [n_dst]
    int* offsets    = counts + n_dst;             // [n_dst + 1]
    int* cursor     = offsets + n_dst + 1;        // [n_dst]
    int* sorted_src = cursor + n_dst;             // [n_edges]

    hipMemsetAsync(counts, 0, (size_t)n_dst * sizeof(int), stream);

    const int B = 256;
    hist_kernel<<<(n_edges + B - 1) / B, B, 0, stream>>>(edge_dst, counts, n_edges);
    scan_kernel<<<1, 1024, 0, stream>>>(counts, offsets, cursor, n_dst);
    scatter_kernel<<<(n_edges + B - 1) / B, B, 0, stream>>>(edge_src, edge_dst,
                                                            cursor, sorted_src, n_edges);
    // 4 nodes per 256-thread block (1 wave each); covers all nodes incl. deg-0
    int nodes_per_block = B / 64;
    int grid = (n_dst + nodes_per_block - 1) / nodes_per_block;
    accum_kernel<<<grid, B, 0, stream>>>(src_emb, offsets, sorted_src, out, n_dst);
}

// Round 3
// 228.276 us; speedup vs baseline: 3.7602x; 1.9095x over previous
//
#include <hip/hip_runtime.h>

// HeteroConv copy_u + segment_sum, CSR-rebuild formulation.
// Round-2 lesson: single-block scan was 231us (53% of total, 1 CU busy).
// Round-3: hierarchical 3-kernel scan (block scan -> scan of block sums ->
// add bases), everything else unchanged.

#define SCAN_T 256
#define SCAN_SEQ 16
#define SCAN_ELEMS (SCAN_T * SCAN_SEQ)  // 4096 elements per block

// ---- phase 1: histogram of edge_dst ----
__global__ void hist_kernel(const int* __restrict__ edst,
                            int* __restrict__ counts, int n) {
    int i = blockIdx.x * blockDim.x + threadIdx.x;
    if (i < n) atomicAdd(&counts[edst[i]], 1);
}

// ---- phase 2a: per-block exclusive scan of counts ----
__global__ void scan_blocks_kernel(const int* __restrict__ counts,
                                   int* __restrict__ offsets,
                                   int* __restrict__ block_sums, int n) {
    __shared__ int lds[SCAN_T];
    int t = threadIdx.x;
    int base = blockIdx.x * SCAN_ELEMS + t * SCAN_SEQ;

    int local[SCAN_SEQ];
    int s = 0;
    for (int k = 0; k < SCAN_SEQ; ++k) {
        int i = base + k;
        int v = (i < n) ? counts[i] : 0;
        local[k] = s;  // exclusive prefix within this thread's run
        s += v;
    }
    lds[t] = s;
    __syncthreads();
    // Hillis-Steele inclusive scan over per-thread sums
    for (int off = 1; off < SCAN_T; off <<= 1) {
        int v = (t >= off) ? lds[t - off] : 0;
        __syncthreads();
        lds[t] += v;
        __syncthreads();
    }
    int thread_base = (t == 0) ? 0 : lds[t - 1];
    for (int k = 0; k < SCAN_SEQ; ++k) {
        int i = base + k;
        if (i < n) offsets[i] = thread_base + local[k];
    }
    if (t == SCAN_T - 1) block_sums[blockIdx.x] = lds[t];
}

// ---- phase 2b: scan block sums (single block; nblocks <= 1024) ----
__global__ void scan_sums_kernel(int* __restrict__ block_sums,
                                 int* __restrict__ total_out, int nblocks) {
    __shared__ int lds[1024];
    int t = threadIdx.x;
    int v = (t < nblocks) ? block_sums[t] : 0;
    lds[t] = v;
    __syncthreads();
    for (int off = 1; off < 1024; off <<= 1) {
        int u = (t >= off) ? lds[t - off] : 0;
        __syncthreads();
        lds[t] += u;
        __syncthreads();
    }
    if (t < nblocks) block_sums[t] = lds[t] - v;  // exclusive base
    if (t == 1023) *total_out = lds[t];           // total edges -> offsets[n]
}

// ---- phase 2c: add block bases; materialize offsets and cursor ----
__global__ void add_bases_kernel(int* __restrict__ offsets,
                                 int* __restrict__ cursor,
                                 const int* __restrict__ block_bases, int n) {
    int t = threadIdx.x;
    int base = blockIdx.x * SCAN_ELEMS + t * SCAN_SEQ;
    int add = block_bases[blockIdx.x];
    for (int k = 0; k < SCAN_SEQ; ++k) {
        int i = base + k;
        if (i < n) {
            int o = offsets[i] + add;
            offsets[i] = o;
            cursor[i] = o;
        }
    }
}

// ---- phase 3: scatter edge_src into dst-sorted positions ----
__global__ void scatter_kernel(const int* __restrict__ esrc,
                               const int* __restrict__ edst,
                               int* __restrict__ cursor,
                               int* __restrict__ sorted_src, int n) {
    int i = blockIdx.x * blockDim.x + threadIdx.x;
    if (i < n) {
        int pos = atomicAdd(&cursor[edst[i]], 1);
        sorted_src[pos] = esrc[i];
    }
}

// ---- phase 4: per-node accumulation. 1 wave per node, lane = feature ----
__global__ void accum_kernel(const float* __restrict__ src_emb,
                             const int* __restrict__ offsets,
                             const int* __restrict__ sorted_src,
                             float* __restrict__ out, int n_dst) {
    int node = blockIdx.x * (blockDim.x >> 6) + (threadIdx.x >> 6);
    int f = threadIdx.x & 63;
    if (node >= n_dst) return;

    int start = offsets[node];
    int end = offsets[node + 1];

    float acc = 0.f;
    for (int j = start; j < end; ++j) {
        int s = sorted_src[j];                 // wave-uniform broadcast load
        acc += src_emb[(size_t)s * 64 + f];    // 64 lanes -> 256B coalesced
    }
    out[(size_t)node * 64 + f] = acc;          // plain store, no atomics
}

// ---- fallback (ws too small): atomic version ----
__global__ void atomic_scatter_kernel(const float* __restrict__ src_emb,
                                      const int* __restrict__ esrc,
                                      const int* __restrict__ edst,
                                      float* __restrict__ out, int n_edges) {
    int tid = blockIdx.x * blockDim.x + threadIdx.x;
    int e = tid >> 4;
    int q = tid & 15;
    if (e >= n_edges) return;
    int s = esrc[e];
    int d = edst[e];
    const float4* srow = reinterpret_cast<const float4*>(src_emb);
    float4 v = srow[(size_t)s * 16 + q];
    float* orow = out + (size_t)d * 64 + (size_t)q * 4;
    atomicAdd(orow + 0, v.x);
    atomicAdd(orow + 1, v.y);
    atomicAdd(orow + 2, v.z);
    atomicAdd(orow + 3, v.w);
}

extern "C" void kernel_launch(void* const* d_in, const int* in_sizes, int n_in,
                              void* d_out, int out_size, void* d_ws, size_t ws_size,
                              hipStream_t stream) {
    const float* src_emb = (const float*)d_in[0];
    const int* edge_src  = (const int*)d_in[1];
    const int* edge_dst  = (const int*)d_in[2];
    float* out = (float*)d_out;

    const int n_edges = in_sizes[1];
    const int n_dst   = out_size / 64;  // D = 64
    const int nscan   = (n_dst + SCAN_ELEMS - 1) / SCAN_ELEMS;  // scan blocks

    size_t need = ((size_t)3 * n_dst + 1 + n_edges + nscan) * sizeof(int);
    if (ws_size < need || nscan > 1024) {
        hipMemsetAsync(d_out, 0, (size_t)out_size * sizeof(float), stream);
        int total = n_edges * 16;
        atomic_scatter_kernel<<<(total + 255) / 256, 256, 0, stream>>>(
            src_emb, edge_src, edge_dst, out, n_edges);
        return;
    }

    int* counts     = (int*)d_ws;                 // [n_dst]
    int* offsets    = counts + n_dst;             // [n_dst + 1]
    int* cursor     = offsets + n_dst + 1;        // [n_dst]
    int* sorted_src = cursor + n_dst;             // [n_edges]
    int* block_sums = sorted_src + n_edges;       // [nscan]

    hipMemsetAsync(counts, 0, (size_t)n_dst * sizeof(int), stream);

    const int B = 256;
    hist_kernel<<<(n_edges + B - 1) / B, B, 0, stream>>>(edge_dst, counts, n_edges);
    scan_blocks_kernel<<<nscan, SCAN_T, 0, stream>>>(counts, offsets, block_sums, n_dst);
    scan_sums_kernel<<<1, 1024, 0, stream>>>(block_sums, offsets + n_dst, n_dst ? nscan : 0);
    add_bases_kernel<<<nscan, SCAN_T, 0, stream>>>(offsets, cursor, block_sums, n_dst);
    scatter_kernel<<<(n_edges + B - 1) / B, B, 0, stream>>>(edge_src, edge_dst,
                                                            cursor, sorted_src, n_edges);
    int nodes_per_block = B / 64;
    int grid = (n_dst + nodes_per_block - 1) / nodes_per_block;
    accum_kernel<<<grid, B, 0, stream>>>(src_emb, offsets, sorted_src, out, n_dst);
}

// Round 4
// 171.008 us; speedup vs baseline: 5.0195x; 1.3349x over previous
//
#include <hip/hip_runtime.h>

// HeteroConv copy_u + segment_sum, CSR-rebuild formulation.
// R2: killed 64M float atomics (858->436us). R3: hierarchical scan (436->228).
// R4: accum with 4-edge-parallel float4 gather per wave (4x MLP, 4x load
// width); int4-vectorized hist/scatter index reads.

#define SCAN_T 256
#define SCAN_SEQ 16
#define SCAN_ELEMS (SCAN_T * SCAN_SEQ)  // 4096 elements per block

// ---- phase 1: histogram of edge_dst (4 edges per thread, int4 load) ----
__global__ void hist_kernel(const int* __restrict__ edst,
                            int* __restrict__ counts, int n) {
    int i = (blockIdx.x * blockDim.x + threadIdx.x) * 4;
    if (i + 3 < n) {
        int4 d = *reinterpret_cast<const int4*>(edst + i);
        atomicAdd(&counts[d.x], 1);
        atomicAdd(&counts[d.y], 1);
        atomicAdd(&counts[d.z], 1);
        atomicAdd(&counts[d.w], 1);
    } else {
        for (int k = 0; k < 4; ++k) {
            int ii = i + k;
            if (ii < n) atomicAdd(&counts[edst[ii]], 1);
        }
    }
}

// ---- phase 2a: per-block exclusive scan of counts ----
__global__ void scan_blocks_kernel(const int* __restrict__ counts,
                                   int* __restrict__ offsets,
                                   int* __restrict__ block_sums, int n) {
    __shared__ int lds[SCAN_T];
    int t = threadIdx.x;
    int base = blockIdx.x * SCAN_ELEMS + t * SCAN_SEQ;

    int local[SCAN_SEQ];
    int s = 0;
    for (int k = 0; k < SCAN_SEQ; ++k) {
        int i = base + k;
        int v = (i < n) ? counts[i] : 0;
        local[k] = s;  // exclusive prefix within this thread's run
        s += v;
    }
    lds[t] = s;
    __syncthreads();
    for (int off = 1; off < SCAN_T; off <<= 1) {
        int v = (t >= off) ? lds[t - off] : 0;
        __syncthreads();
        lds[t] += v;
        __syncthreads();
    }
    int thread_base = (t == 0) ? 0 : lds[t - 1];
    for (int k = 0; k < SCAN_SEQ; ++k) {
        int i = base + k;
        if (i < n) offsets[i] = thread_base + local[k];
    }
    if (t == SCAN_T - 1) block_sums[blockIdx.x] = lds[t];
}

// ---- phase 2b: scan block sums (single block; nblocks <= 1024) ----
__global__ void scan_sums_kernel(int* __restrict__ block_sums,
                                 int* __restrict__ total_out, int nblocks) {
    __shared__ int lds[1024];
    int t = threadIdx.x;
    int v = (t < nblocks) ? block_sums[t] : 0;
    lds[t] = v;
    __syncthreads();
    for (int off = 1; off < 1024; off <<= 1) {
        int u = (t >= off) ? lds[t - off] : 0;
        __syncthreads();
        lds[t] += u;
        __syncthreads();
    }
    if (t < nblocks) block_sums[t] = lds[t] - v;  // exclusive base
    if (t == 1023) *total_out = lds[t];           // total edges -> offsets[n]
}

// ---- phase 2c: add block bases; materialize offsets and cursor ----
__global__ void add_bases_kernel(int* __restrict__ offsets,
                                 int* __restrict__ cursor,
                                 const int* __restrict__ block_bases, int n) {
    int t = threadIdx.x;
    int base = blockIdx.x * SCAN_ELEMS + t * SCAN_SEQ;
    int add = block_bases[blockIdx.x];
    for (int k = 0; k < SCAN_SEQ; ++k) {
        int i = base + k;
        if (i < n) {
            int o = offsets[i] + add;
            offsets[i] = o;
            cursor[i] = o;
        }
    }
}

// ---- phase 3: scatter edge_src into dst-sorted positions (4/thread) ----
__global__ void scatter_kernel(const int* __restrict__ esrc,
                               const int* __restrict__ edst,
                               int* __restrict__ cursor,
                               int* __restrict__ sorted_src, int n) {
    int i = (blockIdx.x * blockDim.x + threadIdx.x) * 4;
    if (i + 3 < n) {
        int4 s = *reinterpret_cast<const int4*>(esrc + i);
        int4 d = *reinterpret_cast<const int4*>(edst + i);
        sorted_src[atomicAdd(&cursor[d.x], 1)] = s.x;
        sorted_src[atomicAdd(&cursor[d.y], 1)] = s.y;
        sorted_src[atomicAdd(&cursor[d.z], 1)] = s.z;
        sorted_src[atomicAdd(&cursor[d.w], 1)] = s.w;
    } else {
        for (int k = 0; k < 4; ++k) {
            int ii = i + k;
            if (ii < n) sorted_src[atomicAdd(&cursor[edst[ii]], 1)] = esrc[ii];
        }
    }
}

// ---- phase 4: per-node accumulation ----
// Wave64 = 4 groups x 16 lanes. Group g processes edge (start+g, +4, ...);
// lane q of a group loads float4 q of the 64-float row (16B/lane, 4 rows =
// 1KB in flight per wave load). Butterfly shfl_xor(16,32) folds the 4
// partial sums; group 0 stores the float4.
__global__ void accum_kernel(const float4* __restrict__ src4,
                             const int* __restrict__ offsets,
                             const int* __restrict__ sorted_src,
                             float4* __restrict__ out4, int n_dst) {
    int node = blockIdx.x * (blockDim.x >> 6) + (threadIdx.x >> 6);
    if (node >= n_dst) return;
    int lane = threadIdx.x & 63;
    int g = lane >> 4;   // edge slot 0..3
    int q = lane & 15;   // float4 index within the row

    int start = offsets[node];
    int end   = offsets[node + 1];

    float4 acc = make_float4(0.f, 0.f, 0.f, 0.f);
    for (int j = start + g; j < end; j += 4) {
        int s = sorted_src[j];
        float4 v = src4[(size_t)s * 16 + q];
        acc.x += v.x; acc.y += v.y; acc.z += v.z; acc.w += v.w;
    }
#pragma unroll
    for (int off = 16; off < 64; off <<= 1) {
        acc.x += __shfl_xor(acc.x, off);
        acc.y += __shfl_xor(acc.y, off);
        acc.z += __shfl_xor(acc.z, off);
        acc.w += __shfl_xor(acc.w, off);
    }
    if (g == 0) out4[(size_t)node * 16 + q] = acc;
}

// ---- fallback (ws too small): atomic version ----
__global__ void atomic_scatter_kernel(const float* __restrict__ src_emb,
                                      const int* __restrict__ esrc,
                                      const int* __restrict__ edst,
                                      float* __restrict__ out, int n_edges) {
    int tid = blockIdx.x * blockDim.x + threadIdx.x;
    int e = tid >> 4;
    int q = tid & 15;
    if (e >= n_edges) return;
    int s = esrc[e];
    int d = edst[e];
    const float4* srow = reinterpret_cast<const float4*>(src_emb);
    float4 v = srow[(size_t)s * 16 + q];
    float* orow = out + (size_t)d * 64 + (size_t)q * 4;
    atomicAdd(orow + 0, v.x);
    atomicAdd(orow + 1, v.y);
    atomicAdd(orow + 2, v.z);
    atomicAdd(orow + 3, v.w);
}

extern "C" void kernel_launch(void* const* d_in, const int* in_sizes, int n_in,
                              void* d_out, int out_size, void* d_ws, size_t ws_size,
                              hipStream_t stream) {
    const float* src_emb = (const float*)d_in[0];
    const int* edge_src  = (const int*)d_in[1];
    const int* edge_dst  = (const int*)d_in[2];
    float* out = (float*)d_out;

    const int n_edges = in_sizes[1];
    const int n_dst   = out_size / 64;  // D = 64
    const int nscan   = (n_dst + SCAN_ELEMS - 1) / SCAN_ELEMS;

    size_t need = ((size_t)3 * n_dst + 1 + n_edges + nscan) * sizeof(int);
    if (ws_size < need || nscan > 1024) {
        hipMemsetAsync(d_out, 0, (size_t)out_size * sizeof(float), stream);
        int total = n_edges * 16;
        atomic_scatter_kernel<<<(total + 255) / 256, 256, 0, stream>>>(
            src_emb, edge_src, edge_dst, out, n_edges);
        return;
    }

    int* counts     = (int*)d_ws;                 // [n_dst]
    int* offsets    = counts + n_dst;             // [n_dst + 1]
    int* cursor     = offsets + n_dst + 1;        // [n_dst]
    int* sorted_src = cursor + n_dst;             // [n_edges]
    int* block_sums = sorted_src + n_edges;       // [nscan]

    hipMemsetAsync(counts, 0, (size_t)n_dst * sizeof(int), stream);

    const int B = 256;
    int ehist = (n_edges + 4 * B - 1) / (4 * B);
    hist_kernel<<<ehist, B, 0, stream>>>(edge_dst, counts, n_edges);
    scan_blocks_kernel<<<nscan, SCAN_T, 0, stream>>>(counts, offsets, block_sums, n_dst);
    scan_sums_kernel<<<1, 1024, 0, stream>>>(block_sums, offsets + n_dst, n_dst ? nscan : 0);
    add_bases_kernel<<<nscan, SCAN_T, 0, stream>>>(offsets, cursor, block_sums, n_dst);
    scatter_kernel<<<ehist, B, 0, stream>>>(edge_src, edge_dst, cursor, sorted_src, n_edges);

    int nodes_per_block = B / 64;
    int grid = (n_dst + nodes_per_block - 1) / nodes_per_block;
    accum_kernel<<<grid, B, 0, stream>>>(
        reinterpret_cast<const float4*>(src_emb), offsets, sorted_src,
        reinterpret_cast<float4*>(out), n_dst);
}

// Round 5
// 129.664 us; speedup vs baseline: 6.6199x; 1.3188x over previous
//
#include <hip/hip_runtime.h>

// HeteroConv copy_u + segment_sum, CSR-rebuild formulation.
// R2: killed 64M float atomics (858->436us). R3: hierarchical scan (436->228).
// R4: 4-edge-parallel float4 accum (228->171). R5: rank-capturing histogram
// (rank[e] = atomicAdd(&counts[dst],1)) makes the scatter position
// deterministic -> scatter has ZERO atomics (it was atomic-throughput bound
// at 68us, same rate as round-1's 13.3us per 1M atomics).

#define SCAN_T 256
#define SCAN_SEQ 16
#define SCAN_ELEMS (SCAN_T * SCAN_SEQ)  // 4096 elements per block

// ---- phase 1: histogram of edge_dst, capturing per-edge rank ----
__global__ void hist_rank_kernel(const int* __restrict__ edst,
                                 int* __restrict__ counts,
                                 int* __restrict__ rank, int n) {
    int i = blockIdx.x * blockDim.x + threadIdx.x;
    if (i < n) {
        int old = atomicAdd(&counts[edst[i]], 1);
        if (rank) rank[i] = old;
    }
}

// ---- phase 2a: per-block exclusive scan of counts ----
__global__ void scan_blocks_kernel(const int* __restrict__ counts,
                                   int* __restrict__ offsets,
                                   int* __restrict__ block_sums, int n) {
    __shared__ int lds[SCAN_T];
    int t = threadIdx.x;
    int base = blockIdx.x * SCAN_ELEMS + t * SCAN_SEQ;

    int local[SCAN_SEQ];
    int s = 0;
    for (int k = 0; k < SCAN_SEQ; ++k) {
        int i = base + k;
        int v = (i < n) ? counts[i] : 0;
        local[k] = s;  // exclusive prefix within this thread's run
        s += v;
    }
    lds[t] = s;
    __syncthreads();
    for (int off = 1; off < SCAN_T; off <<= 1) {
        int v = (t >= off) ? lds[t - off] : 0;
        __syncthreads();
        lds[t] += v;
        __syncthreads();
    }
    int thread_base = (t == 0) ? 0 : lds[t - 1];
    for (int k = 0; k < SCAN_SEQ; ++k) {
        int i = base + k;
        if (i < n) offsets[i] = thread_base + local[k];
    }
    if (t == SCAN_T - 1) block_sums[blockIdx.x] = lds[t];
}

// ---- phase 2b: scan block sums (single block; nblocks <= 1024) ----
__global__ void scan_sums_kernel(int* __restrict__ block_sums,
                                 int* __restrict__ total_out, int nblocks) {
    __shared__ int lds[1024];
    int t = threadIdx.x;
    int v = (t < nblocks) ? block_sums[t] : 0;
    lds[t] = v;
    __syncthreads();
    for (int off = 1; off < 1024; off <<= 1) {
        int u = (t >= off) ? lds[t - off] : 0;
        __syncthreads();
        lds[t] += u;
        __syncthreads();
    }
    if (t < nblocks) block_sums[t] = lds[t] - v;  // exclusive base
    if (t == 1023) *total_out = lds[t];           // total edges -> offsets[n]
}

// ---- phase 2c: add block bases (cursor optional, only for tier-2) ----
__global__ void add_bases_kernel(int* __restrict__ offsets,
                                 int* __restrict__ cursor,
                                 const int* __restrict__ block_bases, int n) {
    int t = threadIdx.x;
    int base = blockIdx.x * SCAN_ELEMS + t * SCAN_SEQ;
    int add = block_bases[blockIdx.x];
    for (int k = 0; k < SCAN_SEQ; ++k) {
        int i = base + k;
        if (i < n) {
            int o = offsets[i] + add;
            offsets[i] = o;
            if (cursor) cursor[i] = o;
        }
    }
}

// ---- phase 3 (tier-1): atomic-free scatter using precomputed rank ----
__global__ void scatter_rank_kernel(const int* __restrict__ esrc,
                                    const int* __restrict__ edst,
                                    const int* __restrict__ rank,
                                    const int* __restrict__ offsets,
                                    int* __restrict__ sorted_src, int n) {
    int i = blockIdx.x * blockDim.x + threadIdx.x;
    if (i < n) {
        sorted_src[offsets[edst[i]] + rank[i]] = esrc[i];
    }
}

// ---- phase 3 (tier-2): atomic-cursor scatter ----
__global__ void scatter_atomic_kernel(const int* __restrict__ esrc,
                                      const int* __restrict__ edst,
                                      int* __restrict__ cursor,
                                      int* __restrict__ sorted_src, int n) {
    int i = blockIdx.x * blockDim.x + threadIdx.x;
    if (i < n) {
        int pos = atomicAdd(&cursor[edst[i]], 1);
        sorted_src[pos] = esrc[i];
    }
}

// ---- phase 4: per-node accumulation ----
// Wave64 = 4 groups x 16 lanes. Group g processes edge (start+g, +4, ...);
// lane q loads float4 q of the row. Butterfly shfl_xor(16,32) folds the 4
// partials; group 0 stores the float4.
__global__ void accum_kernel(const float4* __restrict__ src4,
                             const int* __restrict__ offsets,
                             const int* __restrict__ sorted_src,
                             float4* __restrict__ out4, int n_dst) {
    int node = blockIdx.x * (blockDim.x >> 6) + (threadIdx.x >> 6);
    if (node >= n_dst) return;
    int lane = threadIdx.x & 63;
    int g = lane >> 4;   // edge slot 0..3
    int q = lane & 15;   // float4 index within the row

    int start = offsets[node];
    int end   = offsets[node + 1];

    float4 acc = make_float4(0.f, 0.f, 0.f, 0.f);
    for (int j = start + g; j < end; j += 4) {
        int s = sorted_src[j];
        float4 v = src4[(size_t)s * 16 + q];
        acc.x += v.x; acc.y += v.y; acc.z += v.z; acc.w += v.w;
    }
#pragma unroll
    for (int off = 16; off < 64; off <<= 1) {
        acc.x += __shfl_xor(acc.x, off);
        acc.y += __shfl_xor(acc.y, off);
        acc.z += __shfl_xor(acc.z, off);
        acc.w += __shfl_xor(acc.w, off);
    }
    if (g == 0) out4[(size_t)node * 16 + q] = acc;
}

// ---- tier-3 fallback: direct atomic version ----
__global__ void atomic_scatter_kernel(const float* __restrict__ src_emb,
                                      const int* __restrict__ esrc,
                                      const int* __restrict__ edst,
                                      float* __restrict__ out, int n_edges) {
    int tid = blockIdx.x * blockDim.x + threadIdx.x;
    int e = tid >> 4;
    int q = tid & 15;
    if (e >= n_edges) return;
    int s = esrc[e];
    int d = edst[e];
    const float4* srow = reinterpret_cast<const float4*>(src_emb);
    float4 v = srow[(size_t)s * 16 + q];
    float* orow = out + (size_t)d * 64 + (size_t)q * 4;
    atomicAdd(orow + 0, v.x);
    atomicAdd(orow + 1, v.y);
    atomicAdd(orow + 2, v.z);
    atomicAdd(orow + 3, v.w);
}

extern "C" void kernel_launch(void* const* d_in, const int* in_sizes, int n_in,
                              void* d_out, int out_size, void* d_ws, size_t ws_size,
                              hipStream_t stream) {
    const float* src_emb = (const float*)d_in[0];
    const int* edge_src  = (const int*)d_in[1];
    const int* edge_dst  = (const int*)d_in[2];
    float* out = (float*)d_out;

    const int n_edges = in_sizes[1];
    const int n_dst   = out_size / 64;  // D = 64
    const int nscan   = (n_dst + SCAN_ELEMS - 1) / SCAN_ELEMS;

    const int B = 256;
    const int egrid = (n_edges + B - 1) / B;             // 1 edge/thread
    const int nodes_per_block = B / 64;
    const int agrid = (n_dst + nodes_per_block - 1) / nodes_per_block;

    // tier-1: offsets[n_dst+1] | rank[E] | sorted_src[E] | block_sums[nscan]
    //         counts aliases sorted_src's first n_dst ints (dead after scan,
    //         clobbered by the scatter that follows).
    size_t need1 = ((size_t)n_dst + 1 + 2 * (size_t)n_edges + nscan) * sizeof(int);
    // tier-2: counts | offsets | cursor | sorted_src | block_sums
    size_t need2 = ((size_t)3 * n_dst + 1 + n_edges + nscan) * sizeof(int);

    if (ws_size >= need1 && nscan <= 1024 && n_dst <= n_edges) {
        int* offsets    = (int*)d_ws;                 // [n_dst + 1]
        int* rank       = offsets + n_dst + 1;        // [n_edges]
        int* sorted_src = rank + n_edges;             // [n_edges]
        int* block_sums = sorted_src + n_edges;       // [nscan]
        int* counts     = sorted_src;                 // alias (n_dst <= n_edges)

        hipMemsetAsync(counts, 0, (size_t)n_dst * sizeof(int), stream);
        hist_rank_kernel<<<egrid, B, 0, stream>>>(edge_dst, counts, rank, n_edges);
        scan_blocks_kernel<<<nscan, SCAN_T, 0, stream>>>(counts, offsets, block_sums, n_dst);
        scan_sums_kernel<<<1, 1024, 0, stream>>>(block_sums, offsets + n_dst, nscan);
        add_bases_kernel<<<nscan, SCAN_T, 0, stream>>>(offsets, nullptr, block_sums, n_dst);
        scatter_rank_kernel<<<egrid, B, 0, stream>>>(edge_src, edge_dst, rank,
                                                     offsets, sorted_src, n_edges);
        accum_kernel<<<agrid, B, 0, stream>>>(
            reinterpret_cast<const float4*>(src_emb), offsets, sorted_src,
            reinterpret_cast<float4*>(out), n_dst);
        return;
    }

    if (ws_size >= need2 && nscan <= 1024) {
        int* counts     = (int*)d_ws;                 // [n_dst]
        int* offsets    = counts + n_dst;             // [n_dst + 1]
        int* cursor     = offsets + n_dst + 1;        // [n_dst]
        int* sorted_src = cursor + n_dst;             // [n_edges]
        int* block_sums = sorted_src + n_edges;       // [nscan]

        hipMemsetAsync(counts, 0, (size_t)n_dst * sizeof(int), stream);
        hist_rank_kernel<<<egrid, B, 0, stream>>>(edge_dst, counts, nullptr, n_edges);
        scan_blocks_kernel<<<nscan, SCAN_T, 0, stream>>>(counts, offsets, block_sums, n_dst);
        scan_sums_kernel<<<1, 1024, 0, stream>>>(block_sums, offsets + n_dst, nscan);
        add_bases_kernel<<<nscan, SCAN_T, 0, stream>>>(offsets, cursor, block_sums, n_dst);
        scatter_atomic_kernel<<<egrid, B, 0, stream>>>(edge_src, edge_dst, cursor,
                                                       sorted_src, n_edges);
        accum_kernel<<<agrid, B, 0, stream>>>(
            reinterpret_cast<const float4*>(src_emb), offsets, sorted_src,
            reinterpret_cast<float4*>(out), n_dst);
        return;
    }

    // tier-3: direct atomic fallback
    hipMemsetAsync(d_out, 0, (size_t)out_size * sizeof(float), stream);
    int total = n_edges * 16;
    atomic_scatter_kernel<<<(total + 255) / 256, 256, 0, stream>>>(
        src_emb, edge_src, edge_dst, out, n_edges);
}

// Round 7
// 116.437 us; speedup vs baseline: 7.3720x; 1.1136x over previous
//
#include <hip/hip_runtime.h>

// HeteroConv copy_u + segment_sum, CSR-rebuild formulation (proven R5 shape).
// R2: CSR kills 64M float atomics (858->436). R3: hierarchical scan (436->228).
// R4: 4-edge-parallel float4 accum (228->171). R5: rank-capturing histogram ->
// atomic-free scatter (171->130). R6 bucket-fuse FAILED validation; reverted.
// R7 (this): within R5 structure -- (1) accum prefetches the next edge index
// so the idx-load no longer serializes with the row gather, (2) add_bases
// kernel removed (bases applied on the fly in scatter/accum), (3) int4
// vectorized hist/scatter.

#define SCAN_T 256
#define SCAN_SEQ 16
#define SCAN_ELEMS (SCAN_T * SCAN_SEQ)  // 4096 = 1<<12 elements per scan block

// ---- phase 1: histogram of edge_dst, capturing per-edge rank (4/thread) ----
__global__ void hist_rank_kernel(const int* __restrict__ edst,
                                 int* __restrict__ counts,
                                 int* __restrict__ rank, int n) {
    int i = (blockIdx.x * blockDim.x + threadIdx.x) * 4;
    if (i + 3 < n) {
        int4 d = *reinterpret_cast<const int4*>(edst + i);
        int4 r;
        r.x = atomicAdd(&counts[d.x], 1);
        r.y = atomicAdd(&counts[d.y], 1);
        r.z = atomicAdd(&counts[d.z], 1);
        r.w = atomicAdd(&counts[d.w], 1);
        if (rank) *reinterpret_cast<int4*>(rank + i) = r;
    } else {
        for (int k = 0; k < 4; ++k) {
            int ii = i + k;
            if (ii < n) {
                int old = atomicAdd(&counts[edst[ii]], 1);
                if (rank) rank[ii] = old;
            }
        }
    }
}

// ---- phase 2a: per-block exclusive scan of counts (intra-block prefix) ----
__global__ void scan_blocks_kernel(const int* __restrict__ counts,
                                   int* __restrict__ offsets,
                                   int* __restrict__ block_sums, int n) {
    __shared__ int lds[SCAN_T];
    int t = threadIdx.x;
    int base = blockIdx.x * SCAN_ELEMS + t * SCAN_SEQ;

    int local[SCAN_SEQ];
    int s = 0;
    for (int k = 0; k < SCAN_SEQ; ++k) {
        int i = base + k;
        int v = (i < n) ? counts[i] : 0;
        local[k] = s;
        s += v;
    }
    lds[t] = s;
    __syncthreads();
    for (int off = 1; off < SCAN_T; off <<= 1) {
        int v = (t >= off) ? lds[t - off] : 0;
        __syncthreads();
        lds[t] += v;
        __syncthreads();
    }
    int thread_base = (t == 0) ? 0 : lds[t - 1];
    for (int k = 0; k < SCAN_SEQ; ++k) {
        int i = base + k;
        if (i < n) offsets[i] = thread_base + local[k];  // intra-block prefix
    }
    if (t == SCAN_T - 1) block_sums[blockIdx.x] = lds[t];
}

// ---- phase 2b: scan block sums in place -> exclusive bases; total ----
__global__ void scan_sums_kernel(int* __restrict__ block_sums,
                                 int* __restrict__ total_out, int nblocks) {
    __shared__ int lds[1024];
    int t = threadIdx.x;
    int v = (t < nblocks) ? block_sums[t] : 0;
    lds[t] = v;
    __syncthreads();
    for (int off = 1; off < 1024; off <<= 1) {
        int u = (t >= off) ? lds[t - off] : 0;
        __syncthreads();
        lds[t] += u;
        __syncthreads();
    }
    if (t < nblocks) block_sums[t] = lds[t] - v;  // exclusive base per block
    if (t == 1023) *total_out = lds[t];           // absolute total -> offsets[n]
}

// ---- phase 2c (tier-2 only): make offsets absolute, fill cursor ----
__global__ void add_bases_kernel(int* __restrict__ offsets,
                                 int* __restrict__ cursor,
                                 const int* __restrict__ block_bases, int n) {
    int t = threadIdx.x;
    int base = blockIdx.x * SCAN_ELEMS + t * SCAN_SEQ;
    int add = block_bases[blockIdx.x];
    for (int k = 0; k < SCAN_SEQ; ++k) {
        int i = base + k;
        if (i < n) {
            int o = offsets[i] + add;
            offsets[i] = o;
            if (cursor) cursor[i] = o;
        }
    }
}

// ---- phase 3 (tier-1): atomic-free scatter, bases applied on the fly ----
__global__ void scatter_rank_kernel(const int* __restrict__ esrc,
                                    const int* __restrict__ edst,
                                    const int* __restrict__ rank,
                                    const int* __restrict__ offsets,
                                    const int* __restrict__ bases,
                                    int* __restrict__ sorted_src, int n) {
    int i = (blockIdx.x * blockDim.x + threadIdx.x) * 4;
    if (i + 3 < n) {
        int4 s = *reinterpret_cast<const int4*>(esrc + i);
        int4 d = *reinterpret_cast<const int4*>(edst + i);
        int4 r = *reinterpret_cast<const int4*>(rank + i);
        sorted_src[offsets[d.x] + bases[d.x >> 12] + r.x] = s.x;
        sorted_src[offsets[d.y] + bases[d.y >> 12] + r.y] = s.y;
        sorted_src[offsets[d.z] + bases[d.z >> 12] + r.z] = s.z;
        sorted_src[offsets[d.w] + bases[d.w >> 12] + r.w] = s.w;
    } else {
        for (int k = 0; k < 4; ++k) {
            int ii = i + k;
            if (ii < n) {
                int d = edst[ii];
                sorted_src[offsets[d] + bases[d >> 12] + rank[ii]] = esrc[ii];
            }
        }
    }
}

// ---- phase 3 (tier-2): atomic-cursor scatter (absolute cursor) ----
__global__ void scatter_atomic_kernel(const int* __restrict__ esrc,
                                      const int* __restrict__ edst,
                                      int* __restrict__ cursor,
                                      int* __restrict__ sorted_src, int n) {
    int i = blockIdx.x * blockDim.x + threadIdx.x;
    if (i < n) {
        int pos = atomicAdd(&cursor[edst[i]], 1);
        sorted_src[pos] = esrc[i];
    }
}

// ---- phase 4: per-node accumulation with index prefetch ----
// Wave64 = 4 groups x 16 lanes; group g handles edges g, g+4, ...; lane q
// loads float4 q of the row. The NEXT edge index is prefetched one iteration
// ahead so the index load overlaps the row gather (was a serial 2-hop chain).
// Butterfly shfl_xor(16,32) folds the 4 partials; group 0 stores.
__global__ void accum_kernel(const float4* __restrict__ src4,
                             const int* __restrict__ offsets,
                             const int* __restrict__ bases,
                             const int* __restrict__ sorted_src,
                             float4* __restrict__ out4, int n_dst) {
    int node = blockIdx.x * (blockDim.x >> 6) + (threadIdx.x >> 6);
    if (node >= n_dst) return;
    int lane = threadIdx.x & 63;
    int g = lane >> 4;
    int q = lane & 15;

    int start = offsets[node] + bases[node >> 12];
    int end = (node + 1 == n_dst)
                  ? offsets[n_dst]                                  // absolute total
                  : offsets[node + 1] + bases[(node + 1) >> 12];

    float4 acc = make_float4(0.f, 0.f, 0.f, 0.f);
    int j = start + g;
    int s_next = (j < end) ? sorted_src[j] : 0;
    for (; j < end; j += 4) {
        int s = s_next;
        if (j + 4 < end) s_next = sorted_src[j + 4];  // overlap with row load
        float4 v = src4[(size_t)s * 16 + q];
        acc.x += v.x; acc.y += v.y; acc.z += v.z; acc.w += v.w;
    }
#pragma unroll
    for (int off = 16; off < 64; off <<= 1) {
        acc.x += __shfl_xor(acc.x, off);
        acc.y += __shfl_xor(acc.y, off);
        acc.z += __shfl_xor(acc.z, off);
        acc.w += __shfl_xor(acc.w, off);
    }
    if (g == 0) out4[(size_t)node * 16 + q] = acc;
}

// ---- tier-3 fallback: direct atomic version ----
__global__ void atomic_scatter_kernel(const float* __restrict__ src_emb,
                                      const int* __restrict__ esrc,
                                      const int* __restrict__ edst,
                                      float* __restrict__ out, int n_edges) {
    int tid = blockIdx.x * blockDim.x + threadIdx.x;
    int e = tid >> 4;
    int q = tid & 15;
    if (e >= n_edges) return;
    int s = esrc[e];
    int d = edst[e];
    const float4* srow = reinterpret_cast<const float4*>(src_emb);
    float4 v = srow[(size_t)s * 16 + q];
    float* orow = out + (size_t)d * 64 + (size_t)q * 4;
    atomicAdd(orow + 0, v.x);
    atomicAdd(orow + 1, v.y);
    atomicAdd(orow + 2, v.z);
    atomicAdd(orow + 3, v.w);
}

extern "C" void kernel_launch(void* const* d_in, const int* in_sizes, int n_in,
                              void* d_out, int out_size, void* d_ws, size_t ws_size,
                              hipStream_t stream) {
    const float* src_emb = (const float*)d_in[0];
    const int* edge_src  = (const int*)d_in[1];
    const int* edge_dst  = (const int*)d_in[2];
    float* out = (float*)d_out;

    const int n_edges = in_sizes[1];
    const int n_dst   = out_size / 64;  // D = 64
    const int nscan   = (n_dst + SCAN_ELEMS - 1) / SCAN_ELEMS;

    const int B = 256;
    const int egrid4 = (n_edges + 4 * B - 1) / (4 * B);   // 4 edges/thread
    const int egrid1 = (n_edges + B - 1) / B;             // 1 edge/thread
    const int nodes_per_block = B / 64;
    const int agrid = (n_dst + nodes_per_block - 1) / nodes_per_block;

    // tier-1 layout: offsets[n_dst+1] (padded to x4 ints for rank's int4
    // alignment) | rank[E] | sorted_src[E] | block_sums[nscan].
    // counts aliases sorted_src (dead after scan; requires n_dst <= n_edges).
    size_t off_pad = ((size_t)n_dst + 1 + 3) & ~(size_t)3;
    size_t need1 = (off_pad + 2 * (size_t)n_edges + nscan) * sizeof(int);
    size_t need2 = ((size_t)3 * n_dst + 1 + n_edges + nscan) * sizeof(int);

    if (ws_size >= need1 && nscan <= 1024 && n_dst <= n_edges &&
        (n_edges & 3) == 0) {
        int* offsets    = (int*)d_ws;                 // [n_dst + 1] (+pad)
        int* rank       = offsets + off_pad;          // [n_edges], 16B-aligned
        int* sorted_src = rank + n_edges;             // [n_edges]
        int* block_sums = sorted_src + n_edges;       // [nscan]
        int* counts     = sorted_src;                 // alias

        hipMemsetAsync(counts, 0, (size_t)n_dst * sizeof(int), stream);
        hist_rank_kernel<<<egrid4, B, 0, stream>>>(edge_dst, counts, rank, n_edges);
        scan_blocks_kernel<<<nscan, SCAN_T, 0, stream>>>(counts, offsets, block_sums, n_dst);
        scan_sums_kernel<<<1, 1024, 0, stream>>>(block_sums, offsets + n_dst, nscan);
        scatter_rank_kernel<<<egrid4, B, 0, stream>>>(edge_src, edge_dst, rank,
                                                      offsets, block_sums,
                                                      sorted_src, n_edges);
        accum_kernel<<<agrid, B, 0, stream>>>(
            reinterpret_cast<const float4*>(src_emb), offsets, block_sums,
            sorted_src, reinterpret_cast<float4*>(out), n_dst);
        return;
    }

    if (ws_size >= need2 && nscan <= 1024) {
        int* counts     = (int*)d_ws;                 // [n_dst]
        int* offsets    = counts + n_dst;             // [n_dst + 1]
        int* cursor     = offsets + n_dst + 1;        // [n_dst]
        int* sorted_src = cursor + n_dst;             // [n_edges]
        int* block_sums = sorted_src + n_edges;       // [nscan]

        hipMemsetAsync(counts, 0, (size_t)n_dst * sizeof(int), stream);
        hist_rank_kernel<<<egrid1 * 0 + egrid4, B, 0, stream>>>(edge_dst, counts,
                                                                nullptr, n_edges);
        scan_blocks_kernel<<<nscan, SCAN_T, 0, stream>>>(counts, offsets, block_sums, n_dst);
        scan_sums_kernel<<<1, 1024, 0, stream>>>(block_sums, offsets + n_dst, nscan);
        add_bases_kernel<<<nscan, SCAN_T, 0, stream>>>(offsets, cursor, block_sums, n_dst);
        scatter_atomic_kernel<<<egrid1, B, 0, stream>>>(edge_src, edge_dst, cursor,
                                                        sorted_src, n_edges);
        // offsets are absolute now; pass zeroed bases
        hipMemsetAsync(block_sums, 0, (size_t)nscan * sizeof(int), stream);
        accum_kernel<<<agrid, B, 0, stream>>>(
            reinterpret_cast<const float4*>(src_emb), offsets, block_sums,
            sorted_src, reinterpret_cast<float4*>(out), n_dst);
        return;
    }

    // tier-3: direct atomic fallback
    hipMemsetAsync(d_out, 0, (size_t)out_size * sizeof(float), stream);
    int total = n_edges * 16;
    atomic_scatter_kernel<<<(total + 255) / 256, 256, 0, stream>>>(
        src_emb, edge_src, edge_dst, out, n_edges);
}